// Round 5
// baseline (627.740 us; speedup 1.0000x reference)
//
#include <hip/hip_runtime.h>
#include <hip/hip_bf16.h>

// LoRA forward on MI355X:
//   out = x @ W^T + 2.0 * (x @ A^T) @ B^T
// W_eff = W + 2*(B@A) in bf16, xb = bf16(x); one bf16 MFMA GEMM
// C[16384,4096] = xb @ W_eff^T, 256x256 8-phase schedule, 32x32x16 MFMA
// (half the instruction count, +15% FLOP/cyc ceiling vs 16x16x32),
// one-phase-ahead frag reads, counted lgkm/vmcnt, chunk-XOR swizzle.

typedef __bf16 bf16;
typedef bf16 bf16x8 __attribute__((ext_vector_type(8)));
typedef float f32x16 __attribute__((ext_vector_type(16)));

typedef __attribute__((address_space(1))) const void* as1cv;
typedef __attribute__((address_space(3))) void* as3v;

constexpr int Mdim = 16384;
constexpr int Ndim = 4096;
constexpr int Kdim = 4096;
constexpr int Rdim = 8;
constexpr float kScale = 2.0f;  // lora_alpha / r = 16/8

__device__ __forceinline__ unsigned short f2bf(float f) {
  union { float f; unsigned u; } v; v.f = f;
  unsigned u = v.u;
  u += 0x7fffu + ((u >> 16) & 1u);   // round-to-nearest-even
  return (unsigned short)(u >> 16);
}

// ---------------- Kernel 1: cast x (f32) -> xb (bf16) ----------------
__global__ void cast_x_kernel(const float4* __restrict__ x4,
                              ushort4* __restrict__ o4, int n4) {
  int i = blockIdx.x * blockDim.x + threadIdx.x;
  int stride = gridDim.x * blockDim.x;
  for (; i < n4; i += stride) {
    float4 v = x4[i];
    ushort4 o;
    o.x = f2bf(v.x); o.y = f2bf(v.y); o.z = f2bf(v.z); o.w = f2bf(v.w);
    o4[i] = o;
  }
}

// ---------------- Kernel 2: W_eff = W + 2*(B@A), cast to bf16 --------
__global__ void make_weff_kernel(const float* __restrict__ W,
                                 const float* __restrict__ A,
                                 const float* __restrict__ Bm,
                                 ushort* __restrict__ weff) {
  int tid = blockIdx.x * blockDim.x + threadIdx.x;
  int kc = tid & 511;       // K/8 = 512
  int n = tid >> 9;
  if (n >= Ndim) return;

  const float* wp = W + (long)n * Kdim + kc * 8;
  float4 w0 = *(const float4*)(wp);
  float4 w1 = *(const float4*)(wp + 4);

  float4 b0 = *(const float4*)(Bm + n * Rdim);
  float4 b1 = *(const float4*)(Bm + n * Rdim + 4);
  float bs[8] = {b0.x, b0.y, b0.z, b0.w, b1.x, b1.y, b1.z, b1.w};

  float l[8] = {0.f, 0.f, 0.f, 0.f, 0.f, 0.f, 0.f, 0.f};
#pragma unroll
  for (int r = 0; r < Rdim; ++r) {
    const float* ap = A + (long)r * Kdim + kc * 8;
    float4 a0 = *(const float4*)(ap);
    float4 a1 = *(const float4*)(ap + 4);
    l[0] += bs[r] * a0.x; l[1] += bs[r] * a0.y;
    l[2] += bs[r] * a0.z; l[3] += bs[r] * a0.w;
    l[4] += bs[r] * a1.x; l[5] += bs[r] * a1.y;
    l[6] += bs[r] * a1.z; l[7] += bs[r] * a1.w;
  }

  float o[8] = {w0.x + kScale * l[0], w0.y + kScale * l[1],
                w0.z + kScale * l[2], w0.w + kScale * l[3],
                w1.x + kScale * l[4], w1.y + kScale * l[5],
                w1.z + kScale * l[6], w1.w + kScale * l[7]};
  uint4 pk;
  pk.x = (unsigned)f2bf(o[0]) | ((unsigned)f2bf(o[1]) << 16);
  pk.y = (unsigned)f2bf(o[2]) | ((unsigned)f2bf(o[3]) << 16);
  pk.z = (unsigned)f2bf(o[4]) | ((unsigned)f2bf(o[5]) << 16);
  pk.w = (unsigned)f2bf(o[6]) | ((unsigned)f2bf(o[7]) << 16);
  *(uint4*)(weff + (long)n * Kdim + kc * 8) = pk;
}

// ---------------- Kernel 3: C = xb @ W_eff^T, 256^2 8-phase ----------
#define BM 256
#define BN 256
#define BK 64
#define NT (Kdim / BK)   // 64 K-tiles

#define SCHED0 __builtin_amdgcn_sched_barrier(0)
#define BAR do { SCHED0; __builtin_amdgcn_s_barrier(); SCHED0; } while (0)
#define VMCNT(n) do { asm volatile("s_waitcnt vmcnt(" #n ")" ::: "memory"); SCHED0; } while (0)
#define LGKM(n) do { asm volatile("s_waitcnt lgkmcnt(" #n ")" ::: "memory"); SCHED0; } while (0)
#define GLOAD(src, dst) \
  __builtin_amdgcn_global_load_lds((as1cv)(src), (as3v)(dst), 16, 0, 0)

// Halves by CONSUMPTION quadrant (phase):
//   A half mh: rows { wr*128 + mh*64 + [0,64) : wr=0,1 }   (128 rows stored)
//   B half nh: rows { wc*64 + nh*32 + [0,32) : wc=0..3 }   (128 rows stored)
// Chunk-XOR swizzle: stored 16B chunk cs of row s holds logical chunk cs^(s&7).
// 32x32x16 frags: A row=lane&31, k=(lane>>5)*8+[0..8); C/D col=lane&31,
// row=(reg&3)+8*(reg>>2)+4*(lane>>5)  [m74/m101].

__global__ __launch_bounds__(512, 2) void gemm256(const bf16* __restrict__ Xb,
                                                  const bf16* __restrict__ Wb,
                                                  float* __restrict__ C) {
  __shared__ bf16 lds[2][2][2][128 * 64];  // [dbuf][A/B][half][8192] = 128 KiB

  const int tid = threadIdx.x;
  const int lane = tid & 63;
  const int wave = tid >> 6;
  const int wr = wave >> 2;    // 0..1  (M half)
  const int wc = wave & 3;     // 0..3  (N quarter)
  const int ar = lane & 31;    // row/col within 32-tile
  const int ah = lane >> 5;    // k-group selector

  // XCD-aware bijective swizzle: 1024 blocks, 8 XCDs, 128 contiguous per XCD
  const int wg = blockIdx.x;
  const int swz = (wg & 7) * 128 + (wg >> 3);
  const int by = swz >> 4;     // 0..63  (M block)
  const int bx = swz & 15;     // 0..15  (N block)
  const int brow = by * BM;
  const int bcol = bx * BN;

  // ---- staging pointers (per thread): storage row sLow, swizzled chunk
  const int sLow = tid >> 3;                       // 0..63
  const int cg = (tid & 7) ^ (sLow & 7);           // logical chunk (involution)
  const bf16* pA = Xb + (long)(brow + sLow) * Kdim + cg * 8;
  const bf16* pB =
      Wb + (long)(bcol + (sLow & 31) + (sLow >> 5) * 64) * Kdim + cg * 8;

#define STAGE_A(buf, h, kt) do {                                              \
    const bf16* s_ = pA + (long)((h) * 64) * Kdim + (((kt) & (NT - 1)) * 64); \
    GLOAD(s_, &lds[buf][0][h][0] + tid * 8);                                  \
    GLOAD(s_ + (long)128 * Kdim, &lds[buf][0][h][4096] + tid * 8);            \
  } while (0)
#define STAGE_B(buf, h, kt) do {                                              \
    const bf16* s_ = pB + (long)((h) * 32) * Kdim + (((kt) & (NT - 1)) * 64); \
    GLOAD(s_, &lds[buf][1][h][0] + tid * 8);                                  \
    GLOAD(s_ + (long)128 * Kdim, &lds[buf][1][h][4096] + tid * 8);            \
  } while (0)

  // ---- frag-read bases (swizzled); key = ar&7 (tile offsets are 0 mod 8)
  const bf16* aBs[2] = {&lds[0][0][0][(wr * 64 + ar) * 64],
                        &lds[1][0][0][(wr * 64 + ar) * 64]};
  const bf16* bBs[2] = {&lds[0][1][0][(wc * 32 + ar) * 64],
                        &lds[1][1][0][(wc * 32 + ar) * 64]};
  int cof[4];   // swizzled element offset of k-step ks chunk (ks*2 + ah)
#pragma unroll
  for (int ks = 0; ks < 4; ++ks) cof[ks] = ((ks * 2 + ah) ^ (ar & 7)) * 8;

  f32x16 acc[4][2];   // [m-tile 32][n-tile 32]
#pragma unroll
  for (int m = 0; m < 4; ++m)
#pragma unroll
    for (int n = 0; n < 2; ++n)
      acc[m][n] = (f32x16){0.f, 0.f, 0.f, 0.f, 0.f, 0.f, 0.f, 0.f,
                           0.f, 0.f, 0.f, 0.f, 0.f, 0.f, 0.f, 0.f};

  bf16x8 aF[2][4];   // [mt within mh][ks]  (8 ds_read_b128)
  bf16x8 bF[2][4];   // [nh][ks]            (4 ds_read_b128 per nh)

#define LDA(buf, mh)                                                          \
  { _Pragma("unroll") for (int mt = 0; mt < 2; ++mt)                          \
    _Pragma("unroll") for (int ks = 0; ks < 4; ++ks)                          \
      aF[mt][ks] = *(const bf16x8*)(aBs[buf] + (mh) * 8192 + mt * 2048 + cof[ks]); }
#define LDB(buf, nh)                                                          \
  { _Pragma("unroll") for (int ks = 0; ks < 4; ++ks)                          \
      bF[nh][ks] = *(const bf16x8*)(bBs[buf] + (nh) * 8192 + cof[ks]); }
#define MFMAQ(mh, nh)                                                         \
  { __builtin_amdgcn_s_setprio(1);                                            \
    _Pragma("unroll") for (int mt = 0; mt < 2; ++mt)                          \
    _Pragma("unroll") for (int ks = 0; ks < 4; ++ks)                          \
      acc[(mh) * 2 + mt][nh] = __builtin_amdgcn_mfma_f32_32x32x16_bf16(       \
          aF[mt][ks], bF[nh][ks], acc[(mh) * 2 + mt][nh], 0, 0, 0);           \
    __builtin_amdgcn_s_setprio(0); }

  // Schedule identical to round 4 (quadrants (0,0)(0,1)(1,1)(1,0); frag
  // reads one phase ahead; P3 cross-tile reads = 8+4 = 12 -> P0 LGKM(4)
  // after issuing LDB's 4; dual vmcnt(6); 1 half-tile staged per phase).
#define TILE(bc, bn, t) do {                                                  \
    /* P0 */                                                                  \
    STAGE_A(bn, 1, (t) + 1);                                                  \
    LDB(bc, 1);                                                               \
    BAR; LGKM(4);                                                             \
    MFMAQ(0, 0); BAR;                                                         \
    /* P1 */                                                                  \
    STAGE_A(bc, 0, (t) + 2);                                                  \
    BAR; LGKM(0);                                                             \
    MFMAQ(0, 1); BAR;                                                         \
    /* P2 */                                                                  \
    LDA(bc, 1);                                                               \
    STAGE_B(bc, 0, (t) + 2);                                                  \
    BAR; LGKM(0);                                                             \
    MFMAQ(1, 1);                                                              \
    VMCNT(6); BAR;                                                            \
    /* P3 */                                                                  \
    MFMAQ(1, 0);                                                              \
    LDA(bn, 0);                                                               \
    LDB(bn, 0);                                                               \
    STAGE_B(bc, 1, (t) + 2);                                                  \
    VMCNT(6); BAR;                                                            \
  } while (0)

  // ---- prologue: tile0 complete + {A-h0,B-h0,B-h1} of tile1, then pre-read
  // tile0's A0/B0 frags (12 reads) to enter steady state.
  STAGE_A(0, 0, 0); STAGE_B(0, 0, 0); STAGE_B(0, 1, 0); STAGE_A(0, 1, 0);
  STAGE_A(1, 0, 1); STAGE_B(1, 0, 1); STAGE_B(1, 1, 1);
  VMCNT(6); BAR;
  LDA(0, 0);
  LDB(0, 0);

#pragma unroll 1
  for (int t = 0; t < NT; t += 2) {
    TILE(0, 1, t);        // tail wrap-dummies land only in dead slots
    TILE(1, 0, t + 1);    // (audited per-slot: staged after last read-wait)
  }
  VMCNT(0);

  // ---- epilogue: 32x32 C/D layout col=lane&31, row=(reg&3)+8*(reg>>2)+4*ah
  const int ccol = bcol + wc * 64 + ar;
  const int crow0 = brow + wr * 128 + 4 * ah;
#pragma unroll
  for (int m = 0; m < 4; ++m) {
#pragma unroll
    for (int n = 0; n < 2; ++n) {
      f32x16 v = acc[m][n];
      long col = ccol + n * 32;
#pragma unroll
      for (int g = 0; g < 4; ++g) {
#pragma unroll
        for (int j = 0; j < 4; ++j) {
          long row = crow0 + m * 32 + g * 8 + j;
          C[row * Ndim + col] = v[g * 4 + j];
        }
      }
    }
  }
}

extern "C" void kernel_launch(void* const* d_in, const int* in_sizes, int n_in,
                              void* d_out, int out_size, void* d_ws,
                              size_t ws_size, hipStream_t stream) {
  const float* x = (const float*)d_in[0];       // [4,4096,4096] -> [M,K]
  const float* W = (const float*)d_in[1];       // [N,K]
  const float* lA = (const float*)d_in[2];      // [R,K]
  const float* lB = (const float*)d_in[3];      // [N,R]
  float* out = (float*)d_out;                   // [M,N] f32

  ushort* xb = (ushort*)d_ws;                          // M*K bf16 = 134 MB
  ushort* weff = xb + (size_t)Mdim * Kdim;             // N*K bf16 = 33.5 MB

  cast_x_kernel<<<2048, 256, 0, stream>>>((const float4*)x, (ushort4*)xb,
                                          (Mdim * Kdim) / 4);
  make_weff_kernel<<<(Ndim * (Kdim / 8)) / 256, 256, 0, stream>>>(W, lA, lB,
                                                                  weff);
  dim3 grid((Mdim / BM) * (Ndim / BN));  // 64*16 = 1024 blocks
  gemm256<<<grid, 512, 0, stream>>>((const bf16*)xb, (const bf16*)weff, out);
}

// Round 6
// 567.437 us; speedup vs baseline: 1.1063x; 1.1063x over previous
//
#include <hip/hip_runtime.h>
#include <hip/hip_bf16.h>

// LoRA forward on MI355X:
//   out = x @ W^T + 2.0 * (x @ A^T) @ B^T
// W_eff = W + 2*(B@A) in bf16, xb = bf16(x); one bf16 MFMA GEMM
// C[16384,4096] = xb @ W_eff^T, 256x256 8-phase schedule, 16x16x32 MFMA
// (round-5's 32x32 shape reverted: it re-introduced 5e7 bank conflicts).
// Round-6: full one-phase-ahead operand preload (dual A-register sets),
// SCHED0 only after waits (rule #18), counted lgkm/vmcnt, chunk-XOR swizzle.

typedef __bf16 bf16;
typedef bf16 bf16x8 __attribute__((ext_vector_type(8)));
typedef float f32x4 __attribute__((ext_vector_type(4)));

typedef __attribute__((address_space(1))) const void* as1cv;
typedef __attribute__((address_space(3))) void* as3v;

constexpr int Mdim = 16384;
constexpr int Ndim = 4096;
constexpr int Kdim = 4096;
constexpr int Rdim = 8;
constexpr float kScale = 2.0f;  // lora_alpha / r = 16/8

__device__ __forceinline__ unsigned short f2bf(float f) {
  union { float f; unsigned u; } v; v.f = f;
  unsigned u = v.u;
  u += 0x7fffu + ((u >> 16) & 1u);   // round-to-nearest-even
  return (unsigned short)(u >> 16);
}

// ---------------- Kernel 1: cast x (f32) -> xb (bf16) ----------------
__global__ void cast_x_kernel(const float4* __restrict__ x4,
                              ushort4* __restrict__ o4, int n4) {
  int i = blockIdx.x * blockDim.x + threadIdx.x;
  int stride = gridDim.x * blockDim.x;
  for (; i < n4; i += stride) {
    float4 v = x4[i];
    ushort4 o;
    o.x = f2bf(v.x); o.y = f2bf(v.y); o.z = f2bf(v.z); o.w = f2bf(v.w);
    o4[i] = o;
  }
}

// ---------------- Kernel 2: W_eff = W + 2*(B@A), cast to bf16 --------
__global__ void make_weff_kernel(const float* __restrict__ W,
                                 const float* __restrict__ A,
                                 const float* __restrict__ Bm,
                                 ushort* __restrict__ weff) {
  int tid = blockIdx.x * blockDim.x + threadIdx.x;
  int kc = tid & 511;       // K/8 = 512
  int n = tid >> 9;
  if (n >= Ndim) return;

  const float* wp = W + (long)n * Kdim + kc * 8;
  float4 w0 = *(const float4*)(wp);
  float4 w1 = *(const float4*)(wp + 4);

  float4 b0 = *(const float4*)(Bm + n * Rdim);
  float4 b1 = *(const float4*)(Bm + n * Rdim + 4);
  float bs[8] = {b0.x, b0.y, b0.z, b0.w, b1.x, b1.y, b1.z, b1.w};

  float l[8] = {0.f, 0.f, 0.f, 0.f, 0.f, 0.f, 0.f, 0.f};
#pragma unroll
  for (int r = 0; r < Rdim; ++r) {
    const float* ap = A + (long)r * Kdim + kc * 8;
    float4 a0 = *(const float4*)(ap);
    float4 a1 = *(const float4*)(ap + 4);
    l[0] += bs[r] * a0.x; l[1] += bs[r] * a0.y;
    l[2] += bs[r] * a0.z; l[3] += bs[r] * a0.w;
    l[4] += bs[r] * a1.x; l[5] += bs[r] * a1.y;
    l[6] += bs[r] * a1.z; l[7] += bs[r] * a1.w;
  }

  float o[8] = {w0.x + kScale * l[0], w0.y + kScale * l[1],
                w0.z + kScale * l[2], w0.w + kScale * l[3],
                w1.x + kScale * l[4], w1.y + kScale * l[5],
                w1.z + kScale * l[6], w1.w + kScale * l[7]};
  uint4 pk;
  pk.x = (unsigned)f2bf(o[0]) | ((unsigned)f2bf(o[1]) << 16);
  pk.y = (unsigned)f2bf(o[2]) | ((unsigned)f2bf(o[3]) << 16);
  pk.z = (unsigned)f2bf(o[4]) | ((unsigned)f2bf(o[5]) << 16);
  pk.w = (unsigned)f2bf(o[6]) | ((unsigned)f2bf(o[7]) << 16);
  *(uint4*)(weff + (long)n * Kdim + kc * 8) = pk;
}

// ---------------- Kernel 3: C = xb @ W_eff^T, 256^2 8-phase ----------
#define BM 256
#define BN 256
#define BK 64
#define NT (Kdim / BK)   // 64 K-tiles

#define SCHED0 __builtin_amdgcn_sched_barrier(0)
#define BAR __builtin_amdgcn_s_barrier()
#define VMCNT(n) asm volatile("s_waitcnt vmcnt(" #n ")" ::: "memory")
// LGKM keeps a trailing SCHED0: rule #18 (MFMA hoists past inline-asm waits)
#define LGKM(n) do { asm volatile("s_waitcnt lgkmcnt(" #n ")" ::: "memory"); SCHED0; } while (0)
#define GLOAD(src, dst) \
  __builtin_amdgcn_global_load_lds((as1cv)(src), (as3v)(dst), 16, 0, 0)

// Halves by CONSUMPTION quadrant (phase):
//   A half mh: rows { wr*128 + mh*64 + [0,64) : wr=0,1 }
//   B half nh: rows { wc*64 + nh*32 + [0,32) : wc=0..3 }
// Chunk-XOR swizzle: stored 16B chunk cs of row s holds logical chunk cs^(s&7).

__global__ __launch_bounds__(512, 2) void gemm256(const bf16* __restrict__ Xb,
                                                  const bf16* __restrict__ Wb,
                                                  float* __restrict__ C) {
  __shared__ bf16 lds[2][2][2][128 * 64];  // [dbuf][A/B][half][8192] = 128 KiB

  const int tid = threadIdx.x;
  const int lane = tid & 63;
  const int wave = tid >> 6;
  const int wr = wave >> 2;    // 0..1  (M half)
  const int wc = wave & 3;     // 0..3  (N quarter)
  const int fr = lane & 15;
  const int fq = lane >> 4;

  // XCD-aware bijective swizzle: 1024 blocks, 8 XCDs, 128 contiguous per XCD
  const int wg = blockIdx.x;
  const int swz = (wg & 7) * 128 + (wg >> 3);
  const int by = swz >> 4;     // 0..63  (M block)
  const int bx = swz & 15;     // 0..15  (N block)
  const int brow = by * BM;
  const int bcol = bx * BN;

  // ---- staging pointers (per thread): storage row sLow, swizzled chunk
  const int sLow = tid >> 3;                       // 0..63
  const int cg = (tid & 7) ^ (sLow & 7);           // logical chunk (involution)
  const bf16* pA = Xb + (long)(brow + sLow) * Kdim + cg * 8;
  const bf16* pB =
      Wb + (long)(bcol + (sLow & 31) + (sLow >> 5) * 64) * Kdim + cg * 8;

#define STAGE_A(buf, h, kt) do {                                              \
    const bf16* s_ = pA + (long)((h) * 64) * Kdim + (((kt) & (NT - 1)) * 64); \
    GLOAD(s_, &lds[buf][0][h][0] + tid * 8);                                  \
    GLOAD(s_ + (long)128 * Kdim, &lds[buf][0][h][4096] + tid * 8);            \
  } while (0)
#define STAGE_B(buf, h, kt) do {                                              \
    const bf16* s_ = pB + (long)((h) * 32) * Kdim + (((kt) & (NT - 1)) * 64); \
    GLOAD(s_, &lds[buf][1][h][0] + tid * 8);                                  \
    GLOAD(s_ + (long)128 * Kdim, &lds[buf][1][h][4096] + tid * 8);            \
  } while (0)

  // ---- frag-read bases (swizzled)
  const bf16* aBs[2] = {&lds[0][0][0][(wr * 64 + fr) * 64],
                        &lds[1][0][0][(wr * 64 + fr) * 64]};
  const bf16* bBs[2] = {&lds[0][1][0][(wc * 32 + fr) * 64],
                        &lds[1][1][0][(wc * 32 + fr) * 64]};
  const int cofs0 = ((fq + 0) ^ (fr & 7)) * 8;   // kk=0 chunk
  const int cofs1 = ((fq + 4) ^ (fr & 7)) * 8;   // kk=1 chunk

  f32x4 acc[8][4];
#pragma unroll
  for (int m = 0; m < 8; ++m)
#pragma unroll
    for (int n = 0; n < 4; ++n)
      acc[m][n] = (f32x4){0.f, 0.f, 0.f, 0.f};

  bf16x8 aF0[4][2];    // A-half-0 frags (read cross-tile at P3)
  bf16x8 aF1[4][2];    // A-half-1 frags (read one phase ahead at P1)
  bf16x8 bF[2][2][2];  // [nh][n2][kk], both nh held across the tile

#define LDA(dst, buf, mh)                                                     \
  { _Pragma("unroll") for (int m4 = 0; m4 < 4; ++m4) {                        \
      dst[m4][0] = *(const bf16x8*)(aBs[buf] + (mh) * 8192 + m4 * 1024 + cofs0); \
      dst[m4][1] = *(const bf16x8*)(aBs[buf] + (mh) * 8192 + m4 * 1024 + cofs1); \
  } }
#define LDB(buf, nh)                                                          \
  { _Pragma("unroll") for (int n2 = 0; n2 < 2; ++n2) {                        \
      bF[nh][n2][0] = *(const bf16x8*)(bBs[buf] + (nh) * 8192 + n2 * 1024 + cofs0); \
      bF[nh][n2][1] = *(const bf16x8*)(bBs[buf] + (nh) * 8192 + n2 * 1024 + cofs1); \
  } }
#define MFMAQ(areg, mh, nh)                                                   \
  { __builtin_amdgcn_s_setprio(1);                                            \
    _Pragma("unroll") for (int m4 = 0; m4 < 4; ++m4)                          \
    _Pragma("unroll") for (int n2 = 0; n2 < 2; ++n2)                          \
    _Pragma("unroll") for (int kk = 0; kk < 2; ++kk)                          \
      acc[(mh) * 4 + m4][(nh) * 2 + n2] =                                     \
          __builtin_amdgcn_mfma_f32_16x16x32_bf16(                            \
              areg[m4][kk], bF[nh][n2][kk], acc[(mh) * 4 + m4][(nh) * 2 + n2],\
              0, 0, 0);                                                       \
    __builtin_amdgcn_s_setprio(0); }

  // Quadrants (0,0)@P0 (0,1)@P1 (1,1)@P2 (1,0)@P3; ALL operands preloaded
  // >=1 phase ahead:
  //   P0: LDB1 issued; LGKM(4) drains P3's 12 cross-tile reads (aF0,bF0).
  //   P1: LDA1 issued (own reg set; old aF1 dead since P3(t-1));
  //       LGKM(8) drains bF1's 4 (phase-old).
  //   P2: LGKM(0) drains aF1's 8 (phase-old); vmcnt(6) certifies t+1's
  //       {A-h0,B-h0,B-h1} (staged P1..P3 of t-1).
  //   P3: MFMA(1,0) waits on nothing; cross-tile reads A0/B0(t+1)->aF0,bF0;
  //       vmcnt(6) certifies A-h1(t+1) (staged P0(t)) before P1(t+1)'s LDA1.
  // LDS WAR: every restage >=2 barriers after its slot's readers drained.
#define TILE(bc, bn, t) do {                                                  \
    /* P0 */                                                                  \
    STAGE_A(bn, 1, (t) + 1);                                                  \
    LDB(bc, 1);                                                               \
    BAR; LGKM(4);                                                             \
    MFMAQ(aF0, 0, 0); BAR;                                                    \
    /* P1 */                                                                  \
    STAGE_A(bc, 0, (t) + 2);                                                  \
    LDA(aF1, bc, 1);                                                          \
    BAR; LGKM(8);                                                             \
    MFMAQ(aF0, 0, 1); BAR;                                                    \
    /* P2 */                                                                  \
    STAGE_B(bc, 0, (t) + 2);                                                  \
    BAR; LGKM(0);                                                             \
    MFMAQ(aF1, 1, 1);                                                         \
    VMCNT(6); BAR;                                                            \
    /* P3 */                                                                  \
    MFMAQ(aF1, 1, 0);                                                         \
    LDA(aF0, bn, 0);                                                          \
    LDB(bn, 0);                                                               \
    STAGE_B(bc, 1, (t) + 2);                                                  \
    VMCNT(6); BAR;                                                            \
  } while (0)

  // ---- prologue: tile0 complete + {A-h0,B-h0,B-h1} of tile1, then pre-read
  // tile0's A0/B0 frags (12 reads outstanding into first P0's LGKM(4)).
  STAGE_A(0, 0, 0); STAGE_B(0, 0, 0); STAGE_B(0, 1, 0); STAGE_A(0, 1, 0);
  STAGE_A(1, 0, 1); STAGE_B(1, 0, 1); STAGE_B(1, 1, 1);
  VMCNT(6); BAR;
  LDA(aF0, 0, 0);
  LDB(0, 0);

#pragma unroll 1
  for (int t = 0; t < NT; t += 2) {
    TILE(0, 1, t);        // tail wrap-dummies land only in dead slots
    TILE(1, 0, t + 1);    // (audited per-slot: staged after last read-wait)
  }
  VMCNT(0);
  LGKM(0);

  // ---- epilogue: C/D layout col=lane&15, row=(lane>>4)*4+reg
  const int crow = brow + wr * 128 + fq * 4;
  const int ccol = bcol + wc * 64 + fr;
#pragma unroll
  for (int m = 0; m < 8; ++m) {
#pragma unroll
    for (int n = 0; n < 4; ++n) {
      f32x4 v = acc[m][n];
      long base = (long)(crow + m * 16) * Ndim + (ccol + n * 16);
      C[base] = v[0];
      C[base + Ndim] = v[1];
      C[base + 2 * (long)Ndim] = v[2];
      C[base + 3 * (long)Ndim] = v[3];
    }
  }
}

extern "C" void kernel_launch(void* const* d_in, const int* in_sizes, int n_in,
                              void* d_out, int out_size, void* d_ws,
                              size_t ws_size, hipStream_t stream) {
  const float* x = (const float*)d_in[0];       // [4,4096,4096] -> [M,K]
  const float* W = (const float*)d_in[1];       // [N,K]
  const float* lA = (const float*)d_in[2];      // [R,K]
  const float* lB = (const float*)d_in[3];      // [N,R]
  float* out = (float*)d_out;                   // [M,N] f32

  ushort* xb = (ushort*)d_ws;                          // M*K bf16 = 134 MB
  ushort* weff = xb + (size_t)Mdim * Kdim;             // N*K bf16 = 33.5 MB

  cast_x_kernel<<<2048, 256, 0, stream>>>((const float4*)x, (ushort4*)xb,
                                          (Mdim * Kdim) / 4);
  make_weff_kernel<<<(Ndim * (Kdim / 8)) / 256, 256, 0, stream>>>(W, lA, lB,
                                                                  weff);
  dim3 grid((Mdim / BM) * (Ndim / BN));  // 64*16 = 1024 blocks
  gemm256<<<grid, 512, 0, stream>>>((const bf16*)xb, (const bf16*)weff, out);
}